// Round 7
// baseline (275.023 us; speedup 1.0000x reference)
//
#include <hip/hip_runtime.h>
#include <hip/hip_bf16.h>

// Problem constants (B=2, S=2048, D=1024, H=16, Dh=64) — I/O float32.
#define BB 2
#define SS 2048
#define DD 1024
#define HH 16
#define N3 3072

typedef __attribute__((ext_vector_type(8))) short bf16x8;   // 8 bf16 in 4 VGPRs
typedef __attribute__((ext_vector_type(4))) float f32x4;

__device__ __forceinline__ float b2f(unsigned short u) {
    return __uint_as_float(((unsigned int)u) << 16);
}
__device__ __forceinline__ unsigned short f2b(float f) {
    unsigned int x = __float_as_uint(f);
    x += 0x7fffu + ((x >> 16) & 1u);   // RNE
    return (unsigned short)(x >> 16);
}
__device__ __forceinline__ unsigned int pack2bf(float a, float b) {
    __hip_bfloat162 h = __float22bfloat162_rn(make_float2(a, b));  // v_cvt_pk_bf16_f32
    return *(unsigned int*)&h;
}
__device__ __forceinline__ void storeC(float* p, float v) { *p = v; }
__device__ __forceinline__ void storeC(unsigned short* p, float v) { *p = f2b(v); }

// async global->LDS, 16B/lane; LDS dest = wave-uniform base + lane*16.
__device__ __forceinline__ void gload_lds16(const void* g, void* l) {
    __builtin_amdgcn_global_load_lds(
        (__attribute__((address_space(1))) void*)g,
        (__attribute__((address_space(3))) void*)l, 16, 0, 0);
}

// ---------------------------------------------------------------------------
// sin/cos table: tab[s][t] = (cos, sin)(s * 10000^(-t/32)), fp32.
// ---------------------------------------------------------------------------
__global__ __launch_bounds__(256) void sincos_tab(float2* __restrict__ tab) {
    int i = blockIdx.x * 256 + threadIdx.x;   // SS*32
    int t = i & 31;
    int s = i >> 5;
    float inv = powf(10000.0f, -(float)t * (1.0f / 32.0f));
    float sn, c;
    sincosf((float)s * inv, &sn, &c);
    tab[i] = make_float2(c, sn);
}

// ---------------------------------------------------------------------------
// fp32 -> bf16 elementwise cast.
// ---------------------------------------------------------------------------
__global__ __launch_bounds__(256) void cast_f32_bf16(
    const float* __restrict__ src, unsigned short* __restrict__ dst)
{
    int i = (blockIdx.x * 256 + threadIdx.x) * 4;
    float4 f = *(const float4*)(src + i);
    uint2 o;
    o.x = pack2bf(f.x, f.y);
    o.y = pack2bf(f.z, f.w);
    *(uint2*)(dst + i) = o;
}

// ---------------------------------------------------------------------------
// fp32 [R][C] -> bf16 [C][R] cast + transpose. 64x64 tile / 256 threads.
// ---------------------------------------------------------------------------
__global__ __launch_bounds__(256) void cast_transpose(
    const float* __restrict__ src, unsigned short* __restrict__ dst,
    int R, int C)
{
    __shared__ unsigned short tile[64][66];
    const int t = threadIdx.x;
    const int c0 = blockIdx.x * 64, r0 = blockIdx.y * 64;
    const int lr = t >> 4;
    const int lc = (t & 15) * 4;
    #pragma unroll
    for (int i = 0; i < 4; ++i) {
        float4 f = *(const float4*)(src + (size_t)(r0 + lr + i * 16) * C + c0 + lc);
        tile[lr + i * 16][lc + 0] = f2b(f.x);
        tile[lr + i * 16][lc + 1] = f2b(f.y);
        tile[lr + i * 16][lc + 2] = f2b(f.z);
        tile[lr + i * 16][lc + 3] = f2b(f.w);
    }
    __syncthreads();
    #pragma unroll
    for (int i = 0; i < 4; ++i) {
        const int wr = lr + i * 16;
        ushort4 o;
        o.x = tile[lc + 0][wr];
        o.y = tile[lc + 1][wr];
        o.z = tile[lc + 2][wr];
        o.w = tile[lc + 3][wr];
        *(ushort4*)(dst + (size_t)(c0 + wr) * R + r0 + lc) = o;
    }
}

// ---------------------------------------------------------------------------
// bf16 MFMA GEMM: C[M,N] = A[M,K] @ Bt[N,K]^T. Tile 128 x TN, BK=32, 4 waves.
// ---------------------------------------------------------------------------
template <typename OutT, int TN>
__global__ __launch_bounds__(256) void gemm_mfma(
    const unsigned short* __restrict__ A,
    const unsigned short* __restrict__ Bt,
    OutT* __restrict__ C,
    int M, int N, int K)
{
    constexpr int NI = TN / 32;
    constexpr int NB = TN / 64;
    __shared__ unsigned short Al[128 * 32];
    __shared__ unsigned short Bl[TN * 32];
    const int tid  = threadIdx.x;
    const int wave = tid >> 6;
    const int lane = tid & 63;
    const int quad = lane >> 4;
    const int l16  = lane & 15;
    const int m0 = blockIdx.y * 128;
    const int n0 = blockIdx.x * TN;
    const int wm = (wave >> 1) * 64;
    const int wn = (wave & 1) * (TN / 2);

    const int srowA = wave * 32 + (lane >> 2);
    const int srowB = wave * (16 * NB) + (lane >> 2);
    const int scol  = (lane & 3) * 8;
    const unsigned short* gA = A  + (size_t)(m0 + srowA) * K + scol;
    const unsigned short* gB = Bt + (size_t)(n0 + srowB) * K + scol;

    f32x4 acc[4][NI];
    #pragma unroll
    for (int mi = 0; mi < 4; ++mi)
        #pragma unroll
        for (int ni = 0; ni < NI; ++ni)
            acc[mi][ni] = (f32x4){0.f, 0.f, 0.f, 0.f};

    for (int k0 = 0; k0 < K; k0 += 32) {
        __syncthreads();
        #pragma unroll
        for (int i = 0; i < 2; ++i)
            gload_lds16(gA + (size_t)i * 16 * K + k0, Al + (wave * 2 + i) * 512);
        #pragma unroll
        for (int i = 0; i < NB; ++i)
            gload_lds16(gB + (size_t)i * 16 * K + k0, Bl + (wave * NB + i) * 512);
        __syncthreads();

        bf16x8 af[4], bfr[NI];
        #pragma unroll
        for (int mi = 0; mi < 4; ++mi)
            af[mi] = *(const bf16x8*)&Al[(wm + mi * 16 + l16) * 32 + quad * 8];
        #pragma unroll
        for (int ni = 0; ni < NI; ++ni)
            bfr[ni] = *(const bf16x8*)&Bl[(wn + ni * 16 + l16) * 32 + quad * 8];
        #pragma unroll
        for (int mi = 0; mi < 4; ++mi)
            #pragma unroll
            for (int ni = 0; ni < NI; ++ni)
                acc[mi][ni] = __builtin_amdgcn_mfma_f32_16x16x32_bf16(
                    af[mi], bfr[ni], acc[mi][ni], 0, 0, 0);
    }

    #pragma unroll
    for (int mi = 0; mi < 4; ++mi) {
        #pragma unroll
        for (int r = 0; r < 4; ++r) {
            const size_t base = (size_t)(m0 + wm + mi * 16 + quad * 4 + r) * N + n0 + wn;
            #pragma unroll
            for (int ni = 0; ni < NI; ++ni)
                storeC(&C[base + ni * 16 + l16], acc[mi][ni][r]);
        }
    }
}

// ---------------------------------------------------------------------------
// RoPE + split. Grid (S/64, H, B), block 256.
// qkv[B,S,3D] bf16 -> q,k [B,H,S,64] bf16 (roped), vt [B,H,64,S] bf16 (v^T).
// ---------------------------------------------------------------------------
__global__ __launch_bounds__(256) void rope_split(
    const unsigned short* __restrict__ qkv,
    const float2* __restrict__ tab,
    unsigned short* __restrict__ qo,
    unsigned short* __restrict__ ko,
    unsigned short* __restrict__ vt)
{
    __shared__ unsigned short Vtile[64][72];   // [d][s_local]

    const int s0 = blockIdx.x * 64;
    const int h  = blockIdx.y;
    const int b  = blockIdx.z;
    const int tid = threadIdx.x;
    const int sl = tid >> 2;
    const int qu = tid & 3;
    const size_t bh = (size_t)b * HH + h;

    const unsigned short* row = qkv + (size_t)(b * SS + s0 + sl) * N3 + h * 64;

    uint4 a0 = *(const uint4*)(row + qu * 8);
    uint4 a1 = *(const uint4*)(row + 32 + qu * 8);
    uint4 b0 = *(const uint4*)(row + DD + qu * 8);
    uint4 b1 = *(const uint4*)(row + DD + 32 + qu * 8);
    uint4 c0 = *(const uint4*)(row + 2 * DD + qu * 8);
    uint4 c1 = *(const uint4*)(row + 2 * DD + 32 + qu * 8);

    float2 cs[8];
    {
        const float4* tp = (const float4*)(tab + (size_t)(s0 + sl) * 32 + qu * 8);
        #pragma unroll
        for (int i = 0; i < 4; ++i) {
            float4 f = tp[i];
            cs[2 * i]     = make_float2(f.x, f.y);
            cs[2 * i + 1] = make_float2(f.z, f.w);
        }
    }

    const unsigned short* pa0 = (const unsigned short*)&a0;
    const unsigned short* pa1 = (const unsigned short*)&a1;
    const unsigned short* pb0 = (const unsigned short*)&b0;
    const unsigned short* pb1 = (const unsigned short*)&b1;
    const unsigned short* pc0 = (const unsigned short*)&c0;
    const unsigned short* pc1 = (const unsigned short*)&c1;

    unsigned short oq1[8], oq2[8], ok1[8], ok2[8];
    #pragma unroll
    for (int j = 0; j < 8; ++j) {
        float c = cs[j].x, sn = cs[j].y;
        float q1 = b2f(pa0[j]), q2 = b2f(pa1[j]);
        float k1 = b2f(pb0[j]), k2 = b2f(pb1[j]);
        oq1[j] = f2b(q1 * c - q2 * sn);
        oq2[j] = f2b(q1 * sn + q2 * c);
        ok1[j] = f2b(k1 * c - k2 * sn);
        ok2[j] = f2b(k1 * sn + k2 * c);
        Vtile[qu * 8 + j][sl]      = pc0[j];
        Vtile[32 + qu * 8 + j][sl] = pc1[j];
    }
    const size_t qoff = (bh * SS + s0 + sl) * 64;
    *(uint4*)(qo + qoff + qu * 8)      = *(const uint4*)oq1;
    *(uint4*)(qo + qoff + 32 + qu * 8) = *(const uint4*)oq2;
    *(uint4*)(ko + qoff + qu * 8)      = *(const uint4*)ok1;
    *(uint4*)(ko + qoff + 32 + qu * 8) = *(const uint4*)ok2;

    __syncthreads();

    const int dr = tid >> 2;
    const int ch = tid & 3;
    uint4 t0 = *(const uint4*)&Vtile[dr][ch * 16];
    uint4 t1 = *(const uint4*)&Vtile[dr][ch * 16 + 8];
    unsigned short* vrow = vt + (bh * 64 + dr) * SS + s0 + ch * 16;
    *(uint4*)vrow       = t0;
    *(uint4*)(vrow + 8) = t1;
}

// ---------------------------------------------------------------------------
// Flash attention v4: S^T formulation, 128-key tiles (KT=128), q-tile 64.
// Halves per-key barrier/drain events and softmax fixed costs vs 64-key tiles.
// Diagonal tiles skip fully-masked 16-key subtiles (st_hi) and dead PV MFMAs.
// q,k: [B,H,S,64] bf16; vt: [B,H,64,S] bf16; y: [B,S,H*64] bf16.
// LDS: Kl 16K + Vl 16K + Pq 17.4K = 50.1 KB -> 3 blocks/CU.
// ---------------------------------------------------------------------------
__global__ __launch_bounds__(256) void flash_attn(
    const unsigned short* __restrict__ q,
    const unsigned short* __restrict__ k,
    const unsigned short* __restrict__ vt,
    unsigned short* __restrict__ y,
    const int* __restrict__ is_causal,
    const unsigned char* __restrict__ attn_mask)
{
    __shared__ unsigned short Kl[128 * 64];     // [key][d], 16B chunks swizzled
    __shared__ unsigned short Vl[64 * 128];     // [d][key], 16B chunks swizzled
    __shared__ unsigned short Pq[4][16 * 136];  // per wave [q][key], stride 136

    const int qt  = (int)gridDim.x - 1 - (int)blockIdx.x;   // heavy-first
    const int h   = blockIdx.y;
    const int b   = blockIdx.z;
    const int tid = threadIdx.x;
    const int wave = tid >> 6;
    const int lane = tid & 63;
    const int quad = lane >> 4;
    const int l16  = lane & 15;

    const size_t bh = (size_t)b * HH + h;
    const int q0 = qt * 64;
    const bool causal = (is_causal[0] != 0);
    const int ntiles = causal ? (qt / 2 + 1) : (SS / 128);

    const float SC = 0.18033688011112042f;   // 0.125 * log2(e)

    // Q fragment (B-operand): B[k=d=quad*8+j][n=q=l16]
    const unsigned short* qrow = q + (bh * SS + q0 + wave * 16 + l16) * 64;
    const bf16x8 qf0 = *(const bf16x8*)(qrow + quad * 8);
    const bf16x8 qf1 = *(const bf16x8*)(qrow + 32 + quad * 8);

    const unsigned short* kbase  = k  + bh * SS * 64;   // [key][d]
    const unsigned short* vtbase = vt + bh * 64 * SS;   // [d][s]

    const int csw = quad ^ (l16 & 7);   // read-side chunk swizzle

    f32x4 O[4];
    #pragma unroll
    for (int st = 0; st < 4; ++st) O[st] = (f32x4){0.f, 0.f, 0.f, 0.f};
    float m_run = -1e30f, l_run = 0.f;

    const int qg = q0 + wave * 16 + l16;   // this lane's q row

    for (int kt = 0; kt < ntiles; ++kt) {
        // ---- stage K (128x64, 16 issues) and V^T (64x128, 16 issues)
        #pragma unroll
        for (int i = 0; i < 4; ++i) {
            const int j = wave * 4 + i;
            {   // K: 8 rows of 128B per issue
                const int R  = j * 8 + (lane >> 3);
                const int cl = (lane & 7) ^ (R & 7);
                gload_lds16(kbase + ((size_t)(kt * 128 + R) * 64 + cl * 8),
                            Kl + j * 512);
            }
            {   // V^T: 4 rows of 256B per issue
                const int R  = j * 4 + (lane >> 4);
                const int cl = (lane & 15) ^ (R & 7);
                gload_lds16(vtbase + ((size_t)R * SS + kt * 128 + cl * 8),
                            Vl + j * 512);
            }
        }
        __syncthreads();

        // active 16-key subtiles (diagonal tile may have trailing dead ones)
        const bool diag = causal && (kt == ntiles - 1);
        const int st_hi = diag ? ((q0 + 64 - kt * 128 + 15) >> 4) : 8;  // 4 or 8
        const int ki_hi = st_hi >> 1;                                    // 2 or 4

        // ---- S^T = K·Q^T : up to 8 key-subtiles; scale into log2 domain
        f32x4 Sf[8];
        #pragma unroll
        for (int st = 0; st < 8; ++st) {
            if (st >= st_hi) continue;
            const unsigned short* kr = &Kl[(st * 16 + l16) * 64];
            bf16x8 kf0 = *(const bf16x8*)(kr + csw * 8);
            bf16x8 kf1 = *(const bf16x8*)(kr + (csw ^ 4) * 8);
            f32x4 s = (f32x4){0.f, 0.f, 0.f, 0.f};
            s = __builtin_amdgcn_mfma_f32_16x16x32_bf16(kf0, qf0, s, 0, 0, 0);
            s = __builtin_amdgcn_mfma_f32_16x16x32_bf16(kf1, qf1, s, 0, 0, 0);
            #pragma unroll
            for (int r = 0; r < 4; ++r) s[r] *= SC;
            Sf[st] = s;
        }

        // ---- mask
        if (diag) {
            #pragma unroll
            for (int st = 0; st < 8; ++st) {
                if (st >= st_hi) continue;
                const int kb0 = kt * 128 + st * 16 + quad * 4;
                #pragma unroll
                for (int r = 0; r < 4; ++r)
                    if (kb0 + r > qg) Sf[st][r] = -1e30f;
            }
        } else if (!causal) {
            #pragma unroll
            for (int st = 0; st < 8; ++st) {
                uchar4 mv = *(const uchar4*)(attn_mask + b * SS + kt * 128
                                             + st * 16 + quad * 4);
                if (!mv.x) Sf[st][0] = -1e30f;
                if (!mv.y) Sf[st][1] = -1e30f;
                if (!mv.z) Sf[st][2] = -1e30f;
                if (!mv.w) Sf[st][3] = -1e30f;
            }
        }

        // ---- online softmax, log2 domain, per-lane scalar state
        float mx = -1e30f;
        #pragma unroll
        for (int st = 0; st < 8; ++st) {
            if (st >= st_hi) continue;
            #pragma unroll
            for (int r = 0; r < 4; ++r) mx = fmaxf(mx, Sf[st][r]);
        }
        mx = fmaxf(mx, __shfl_xor(mx, 16));
        mx = fmaxf(mx, __shfl_xor(mx, 32));
        const float mnew = fmaxf(m_run, mx);
        const float alpha = exp2f(m_run - mnew);
        m_run = mnew;

        float lsum = 0.f;
        #pragma unroll
        for (int st = 0; st < 8; ++st) {
            if (st >= st_hi) continue;
            #pragma unroll
            for (int r = 0; r < 4; ++r) {
                float p = exp2f(Sf[st][r] - mnew);
                Sf[st][r] = p;
                lsum += p;
            }
        }
        lsum += __shfl_xor(lsum, 16);
        lsum += __shfl_xor(lsum, 32);
        l_run = l_run * alpha + lsum;

        #pragma unroll
        for (int st = 0; st < 4; ++st)
            #pragma unroll
            for (int r = 0; r < 4; ++r) O[st][r] *= alpha;

        // ---- P^T -> per-wave LDS (packed bf16 pairs; zero for dead subtiles)
        #pragma unroll
        for (int st = 0; st < 8; ++st) {
            uint2 pk;
            if (st < st_hi) {
                pk.x = pack2bf(Sf[st][0], Sf[st][1]);
                pk.y = pack2bf(Sf[st][2], Sf[st][3]);
            } else {
                pk.x = 0; pk.y = 0;
            }
            *(uint2*)&Pq[wave][l16 * 136 + st * 16 + quad * 4] = pk;
        }
        // same-wave LDS round-trip: in-order DS pipe, no barrier needed

        bf16x8 pf[4];
        #pragma unroll
        for (int ki = 0; ki < 4; ++ki)
            pf[ki] = *(const bf16x8*)&Pq[wave][l16 * 136 + ki * 32 + quad * 8];

        // ---- O^T += V^T·P^T : 4 d-subtiles x up-to-4 key-chunks
        #pragma unroll
        for (int st = 0; st < 4; ++st) {
            const unsigned short* vr = &Vl[(st * 16 + l16) * 128];
            #pragma unroll
            for (int ki = 0; ki < 4; ++ki) {
                if (ki >= ki_hi) continue;
                const int cp = ((ki * 4 + quad) ^ (l16 & 7)) * 8;
                bf16x8 vf = *(const bf16x8*)(vr + cp);
                O[st] = __builtin_amdgcn_mfma_f32_16x16x32_bf16(vf, pf[ki], O[st], 0, 0, 0);
            }
        }
        __syncthreads();   // all waves done reading Kl/Vl before restage
    }

    // ---- epilogue: lane owns q = qg, d = st*16+quad*4+r
    const float inv = 1.0f / l_run;
    unsigned short* yrow = y + ((size_t)b * SS + qg) * DD + h * 64;
    #pragma unroll
    for (int st = 0; st < 4; ++st) {
        uint2 o;
        o.x = pack2bf(O[st][0] * inv, O[st][1] * inv);
        o.y = pack2bf(O[st][2] * inv, O[st][3] * inv);
        *(uint2*)(yrow + st * 16 + quad * 4) = o;
    }
}

// ---------------------------------------------------------------------------
// Workspace: xb/yb (aliased) | w1t | w2t | qkv | qb | kb | vt | tab. ~67.6 MB.
// ---------------------------------------------------------------------------
extern "C" void kernel_launch(void* const* d_in, const int* in_sizes, int n_in,
                              void* d_out, int out_size, void* d_ws, size_t ws_size,
                              hipStream_t stream) {
    const float* x      = (const float*)d_in[0];
    const float* qkv_w  = (const float*)d_in[1];
    const float* out_w  = (const float*)d_in[2];
    const unsigned char* mask = (const unsigned char*)d_in[3];
    const int*   is_c   = (const int*)d_in[4];
    float* out = (float*)d_out;

    unsigned short* xb  = (unsigned short*)d_ws;             // aliased with yb
    unsigned short* w1t = xb  + (size_t)4096 * 1024;
    unsigned short* w2t = w1t + (size_t)3072 * 1024;
    unsigned short* qkv = w2t + (size_t)1024 * 1024;
    unsigned short* qb  = qkv + (size_t)4096 * 3072;
    unsigned short* kb  = qb  + (size_t)BB * HH * SS * 64;
    unsigned short* vt  = kb  + (size_t)BB * HH * SS * 64;
    float2* tab = (float2*)(vt + (size_t)BB * HH * SS * 64);
    unsigned short* yb = xb;   // x dead after GEMM1

    sincos_tab<<<(SS * 32) / 256, 256, 0, stream>>>(tab);
    cast_f32_bf16<<<(4096 * 1024) / 1024, 256, 0, stream>>>(x, xb);
    cast_transpose<<<dim3(N3 / 64, DD / 64), 256, 0, stream>>>(qkv_w, w1t, DD, N3);
    cast_transpose<<<dim3(DD / 64, DD / 64), 256, 0, stream>>>(out_w, w2t, DD, DD);

    // GEMM1: qkv = x @ qkv_w  (M=4096, N=3072, K=1024), tile 128x128
    gemm_mfma<unsigned short, 128><<<dim3(N3 / 128, 4096 / 128), 256, 0, stream>>>(
        xb, w1t, qkv, 4096, N3, DD);

    // RoPE + split: q,k [B,H,S,64]; v^T [B,H,64,S]
    rope_split<<<dim3(SS / 64, HH, BB), 256, 0, stream>>>(qkv, tab, qb, kb, vt);

    // Flash attention (S^T form, 128-key tiles) -> y [B,S,D] bf16
    flash_attn<<<dim3(SS / 64, HH, BB), 256, 0, stream>>>(qb, kb, vt, yb, is_c, mask);

    // GEMM2: out = y @ out_w  (M=4096, N=1024, K=1024), tile 128x64 -> 512 blocks
    gemm_mfma<float, 64><<<dim3(DD / 64, 4096 / 128), 256, 0, stream>>>(
        yb, w2t, out, 4096, DD, DD);
}

// Round 8
// 218.439 us; speedup vs baseline: 1.2590x; 1.2590x over previous
//
#include <hip/hip_runtime.h>
#include <hip/hip_bf16.h>

// Problem constants (B=2, S=2048, D=1024, H=16, Dh=64) — I/O float32.
#define BB 2
#define SS 2048
#define DD 1024
#define HH 16
#define N3 3072

typedef __attribute__((ext_vector_type(8))) short bf16x8;   // 8 bf16 in 4 VGPRs
typedef __attribute__((ext_vector_type(4))) float f32x4;

__device__ __forceinline__ float b2f(unsigned short u) {
    return __uint_as_float(((unsigned int)u) << 16);
}
__device__ __forceinline__ unsigned short f2b(float f) {
    unsigned int x = __float_as_uint(f);
    x += 0x7fffu + ((x >> 16) & 1u);   // RNE
    return (unsigned short)(x >> 16);
}
__device__ __forceinline__ unsigned int pack2bf(float a, float b) {
    __hip_bfloat162 h = __float22bfloat162_rn(make_float2(a, b));  // v_cvt_pk_bf16_f32
    return *(unsigned int*)&h;
}
__device__ __forceinline__ void storeC(float* p, float v) { *p = v; }
__device__ __forceinline__ void storeC(unsigned short* p, float v) { *p = f2b(v); }

// async global->LDS, 16B/lane; LDS dest = wave-uniform base + lane*16.
__device__ __forceinline__ void gload_lds16(const void* g, void* l) {
    __builtin_amdgcn_global_load_lds(
        (__attribute__((address_space(1))) void*)g,
        (__attribute__((address_space(3))) void*)l, 16, 0, 0);
}

// ---------------------------------------------------------------------------
// sin/cos table: tab[s][t] = (cos, sin)(s * 10000^(-t/32)), fp32.
// ---------------------------------------------------------------------------
__global__ __launch_bounds__(256) void sincos_tab(float2* __restrict__ tab) {
    int i = blockIdx.x * 256 + threadIdx.x;   // SS*32
    int t = i & 31;
    int s = i >> 5;
    float inv = powf(10000.0f, -(float)t * (1.0f / 32.0f));
    float sn, c;
    sincosf((float)s * inv, &sn, &c);
    tab[i] = make_float2(c, sn);
}

// ---------------------------------------------------------------------------
// fp32 -> bf16 elementwise cast.
// ---------------------------------------------------------------------------
__global__ __launch_bounds__(256) void cast_f32_bf16(
    const float* __restrict__ src, unsigned short* __restrict__ dst)
{
    int i = (blockIdx.x * 256 + threadIdx.x) * 4;
    float4 f = *(const float4*)(src + i);
    uint2 o;
    o.x = pack2bf(f.x, f.y);
    o.y = pack2bf(f.z, f.w);
    *(uint2*)(dst + i) = o;
}

// ---------------------------------------------------------------------------
// fp32 [R][C] -> bf16 [C][R] cast + transpose. 64x64 tile / 256 threads.
// ---------------------------------------------------------------------------
__global__ __launch_bounds__(256) void cast_transpose(
    const float* __restrict__ src, unsigned short* __restrict__ dst,
    int R, int C)
{
    __shared__ unsigned short tile[64][66];
    const int t = threadIdx.x;
    const int c0 = blockIdx.x * 64, r0 = blockIdx.y * 64;
    const int lr = t >> 4;
    const int lc = (t & 15) * 4;
    #pragma unroll
    for (int i = 0; i < 4; ++i) {
        float4 f = *(const float4*)(src + (size_t)(r0 + lr + i * 16) * C + c0 + lc);
        tile[lr + i * 16][lc + 0] = f2b(f.x);
        tile[lr + i * 16][lc + 1] = f2b(f.y);
        tile[lr + i * 16][lc + 2] = f2b(f.z);
        tile[lr + i * 16][lc + 3] = f2b(f.w);
    }
    __syncthreads();
    #pragma unroll
    for (int i = 0; i < 4; ++i) {
        const int wr = lr + i * 16;
        ushort4 o;
        o.x = tile[lc + 0][wr];
        o.y = tile[lc + 1][wr];
        o.z = tile[lc + 2][wr];
        o.w = tile[lc + 3][wr];
        *(ushort4*)(dst + (size_t)(c0 + wr) * R + r0 + lc) = o;
    }
}

// ---------------------------------------------------------------------------
// bf16 MFMA GEMM: C[M,N] = A[M,K] @ Bt[N,K]^T. Tile 128 x TN, BK=32, 4 waves.
// ---------------------------------------------------------------------------
template <typename OutT, int TN>
__global__ __launch_bounds__(256) void gemm_mfma(
    const unsigned short* __restrict__ A,
    const unsigned short* __restrict__ Bt,
    OutT* __restrict__ C,
    int M, int N, int K)
{
    constexpr int NI = TN / 32;
    constexpr int NB = TN / 64;
    __shared__ unsigned short Al[128 * 32];
    __shared__ unsigned short Bl[TN * 32];
    const int tid  = threadIdx.x;
    const int wave = tid >> 6;
    const int lane = tid & 63;
    const int quad = lane >> 4;
    const int l16  = lane & 15;
    const int m0 = blockIdx.y * 128;
    const int n0 = blockIdx.x * TN;
    const int wm = (wave >> 1) * 64;
    const int wn = (wave & 1) * (TN / 2);

    const int srowA = wave * 32 + (lane >> 2);
    const int srowB = wave * (16 * NB) + (lane >> 2);
    const int scol  = (lane & 3) * 8;
    const unsigned short* gA = A  + (size_t)(m0 + srowA) * K + scol;
    const unsigned short* gB = Bt + (size_t)(n0 + srowB) * K + scol;

    f32x4 acc[4][NI];
    #pragma unroll
    for (int mi = 0; mi < 4; ++mi)
        #pragma unroll
        for (int ni = 0; ni < NI; ++ni)
            acc[mi][ni] = (f32x4){0.f, 0.f, 0.f, 0.f};

    for (int k0 = 0; k0 < K; k0 += 32) {
        __syncthreads();
        #pragma unroll
        for (int i = 0; i < 2; ++i)
            gload_lds16(gA + (size_t)i * 16 * K + k0, Al + (wave * 2 + i) * 512);
        #pragma unroll
        for (int i = 0; i < NB; ++i)
            gload_lds16(gB + (size_t)i * 16 * K + k0, Bl + (wave * NB + i) * 512);
        __syncthreads();

        bf16x8 af[4], bfr[NI];
        #pragma unroll
        for (int mi = 0; mi < 4; ++mi)
            af[mi] = *(const bf16x8*)&Al[(wm + mi * 16 + l16) * 32 + quad * 8];
        #pragma unroll
        for (int ni = 0; ni < NI; ++ni)
            bfr[ni] = *(const bf16x8*)&Bl[(wn + ni * 16 + l16) * 32 + quad * 8];
        #pragma unroll
        for (int mi = 0; mi < 4; ++mi)
            #pragma unroll
            for (int ni = 0; ni < NI; ++ni)
                acc[mi][ni] = __builtin_amdgcn_mfma_f32_16x16x32_bf16(
                    af[mi], bfr[ni], acc[mi][ni], 0, 0, 0);
    }

    #pragma unroll
    for (int mi = 0; mi < 4; ++mi) {
        #pragma unroll
        for (int r = 0; r < 4; ++r) {
            const size_t base = (size_t)(m0 + wm + mi * 16 + quad * 4 + r) * N + n0 + wn;
            #pragma unroll
            for (int ni = 0; ni < NI; ++ni)
                storeC(&C[base + ni * 16 + l16], acc[mi][ni][r]);
        }
    }
}

// ---------------------------------------------------------------------------
// RoPE + split. Grid (S/64, H, B), block 256.
// qkv[B,S,3D] bf16 -> q,k [B,H,S,64] bf16 (roped), vt [B,H,64,S] bf16 (v^T).
// ---------------------------------------------------------------------------
__global__ __launch_bounds__(256) void rope_split(
    const unsigned short* __restrict__ qkv,
    const float2* __restrict__ tab,
    unsigned short* __restrict__ qo,
    unsigned short* __restrict__ ko,
    unsigned short* __restrict__ vt)
{
    __shared__ unsigned short Vtile[64][72];   // [d][s_local]

    const int s0 = blockIdx.x * 64;
    const int h  = blockIdx.y;
    const int b  = blockIdx.z;
    const int tid = threadIdx.x;
    const int sl = tid >> 2;
    const int qu = tid & 3;
    const size_t bh = (size_t)b * HH + h;

    const unsigned short* row = qkv + (size_t)(b * SS + s0 + sl) * N3 + h * 64;

    uint4 a0 = *(const uint4*)(row + qu * 8);
    uint4 a1 = *(const uint4*)(row + 32 + qu * 8);
    uint4 b0 = *(const uint4*)(row + DD + qu * 8);
    uint4 b1 = *(const uint4*)(row + DD + 32 + qu * 8);
    uint4 c0 = *(const uint4*)(row + 2 * DD + qu * 8);
    uint4 c1 = *(const uint4*)(row + 2 * DD + 32 + qu * 8);

    float2 cs[8];
    {
        const float4* tp = (const float4*)(tab + (size_t)(s0 + sl) * 32 + qu * 8);
        #pragma unroll
        for (int i = 0; i < 4; ++i) {
            float4 f = tp[i];
            cs[2 * i]     = make_float2(f.x, f.y);
            cs[2 * i + 1] = make_float2(f.z, f.w);
        }
    }

    const unsigned short* pa0 = (const unsigned short*)&a0;
    const unsigned short* pa1 = (const unsigned short*)&a1;
    const unsigned short* pb0 = (const unsigned short*)&b0;
    const unsigned short* pb1 = (const unsigned short*)&b1;
    const unsigned short* pc0 = (const unsigned short*)&c0;
    const unsigned short* pc1 = (const unsigned short*)&c1;

    unsigned short oq1[8], oq2[8], ok1[8], ok2[8];
    #pragma unroll
    for (int j = 0; j < 8; ++j) {
        float c = cs[j].x, sn = cs[j].y;
        float q1 = b2f(pa0[j]), q2 = b2f(pa1[j]);
        float k1 = b2f(pb0[j]), k2 = b2f(pb1[j]);
        oq1[j] = f2b(q1 * c - q2 * sn);
        oq2[j] = f2b(q1 * sn + q2 * c);
        ok1[j] = f2b(k1 * c - k2 * sn);
        ok2[j] = f2b(k1 * sn + k2 * c);
        Vtile[qu * 8 + j][sl]      = pc0[j];
        Vtile[32 + qu * 8 + j][sl] = pc1[j];
    }
    const size_t qoff = (bh * SS + s0 + sl) * 64;
    *(uint4*)(qo + qoff + qu * 8)      = *(const uint4*)oq1;
    *(uint4*)(qo + qoff + 32 + qu * 8) = *(const uint4*)oq2;
    *(uint4*)(ko + qoff + qu * 8)      = *(const uint4*)ok1;
    *(uint4*)(ko + qoff + 32 + qu * 8) = *(const uint4*)ok2;

    __syncthreads();

    const int dr = tid >> 2;
    const int ch = tid & 3;
    uint4 t0 = *(const uint4*)&Vtile[dr][ch * 16];
    uint4 t1 = *(const uint4*)&Vtile[dr][ch * 16 + 8];
    unsigned short* vrow = vt + (bh * 64 + dr) * SS + s0 + ch * 16;
    *(uint4*)vrow       = t0;
    *(uint4*)(vrow + 8) = t1;
}

// ---------------------------------------------------------------------------
// One 64-key attention step for one 16-row q fragment (S^T formulation).
// ---------------------------------------------------------------------------
__device__ __forceinline__ void attn_step(
    const unsigned short* __restrict__ Kb,   // K tile [key][64], swizzled
    const unsigned short* __restrict__ Vb,   // V^T tile [d][64], swizzled
    unsigned short* __restrict__ PqW,        // this wave's P buf, stride 72
    const bf16x8 qf0, const bf16x8 qf1,
    f32x4 O[4], float& m_run, float& l_run,
    bool diag, const unsigned char* mrow,    // mrow != nullptr => non-causal mask
    int kt, int quad, int l16, int csw, int qg)
{
    const float SC = 0.18033688011112042f;   // 0.125 * log2(e)

    // S^T = K·Q^T : 4 key-subtiles
    f32x4 Sf[4];
    #pragma unroll
    for (int st = 0; st < 4; ++st) {
        const unsigned short* kr = &Kb[(st * 16 + l16) * 64];
        bf16x8 kf0 = *(const bf16x8*)(kr + csw * 8);
        bf16x8 kf1 = *(const bf16x8*)(kr + (csw ^ 4) * 8);
        f32x4 s = (f32x4){0.f, 0.f, 0.f, 0.f};
        s = __builtin_amdgcn_mfma_f32_16x16x32_bf16(kf0, qf0, s, 0, 0, 0);
        s = __builtin_amdgcn_mfma_f32_16x16x32_bf16(kf1, qf1, s, 0, 0, 0);
        #pragma unroll
        for (int r = 0; r < 4; ++r) s[r] *= SC;
        Sf[st] = s;
    }

    if (diag) {
        #pragma unroll
        for (int st = 0; st < 4; ++st) {
            const int kb0 = kt * 64 + st * 16 + quad * 4;
            #pragma unroll
            for (int r = 0; r < 4; ++r)
                if (kb0 + r > qg) Sf[st][r] = -1e30f;
        }
    } else if (mrow) {
        #pragma unroll
        for (int st = 0; st < 4; ++st) {
            uchar4 mv = *(const uchar4*)(mrow + st * 16 + quad * 4);
            if (!mv.x) Sf[st][0] = -1e30f;
            if (!mv.y) Sf[st][1] = -1e30f;
            if (!mv.z) Sf[st][2] = -1e30f;
            if (!mv.w) Sf[st][3] = -1e30f;
        }
    }

    // online softmax (log2 domain), per-lane scalar state
    float mx = Sf[0][0];
    #pragma unroll
    for (int st = 0; st < 4; ++st)
        #pragma unroll
        for (int r = 0; r < 4; ++r) mx = fmaxf(mx, Sf[st][r]);
    mx = fmaxf(mx, __shfl_xor(mx, 16));
    mx = fmaxf(mx, __shfl_xor(mx, 32));
    const float mnew = fmaxf(m_run, mx);
    const float alpha = exp2f(m_run - mnew);
    m_run = mnew;

    float lsum = 0.f;
    #pragma unroll
    for (int st = 0; st < 4; ++st)
        #pragma unroll
        for (int r = 0; r < 4; ++r) {
            float p = exp2f(Sf[st][r] - mnew);
            Sf[st][r] = p;
            lsum += p;
        }
    lsum += __shfl_xor(lsum, 16);
    lsum += __shfl_xor(lsum, 32);
    l_run = l_run * alpha + lsum;

    #pragma unroll
    for (int st = 0; st < 4; ++st)
        #pragma unroll
        for (int r = 0; r < 4; ++r) O[st][r] *= alpha;

    // P^T -> per-wave LDS (in-order DS pipe: no barrier needed)
    #pragma unroll
    for (int st = 0; st < 4; ++st) {
        uint2 pk;
        pk.x = pack2bf(Sf[st][0], Sf[st][1]);
        pk.y = pack2bf(Sf[st][2], Sf[st][3]);
        *(uint2*)&PqW[l16 * 72 + st * 16 + quad * 4] = pk;
    }
    bf16x8 pf0 = *(const bf16x8*)&PqW[l16 * 72 + quad * 8];
    bf16x8 pf1 = *(const bf16x8*)&PqW[l16 * 72 + 32 + quad * 8];

    // O^T += V^T·P^T
    #pragma unroll
    for (int st = 0; st < 4; ++st) {
        const unsigned short* vr = &Vb[(st * 16 + l16) * 64];
        bf16x8 vf0 = *(const bf16x8*)(vr + csw * 8);
        bf16x8 vf1 = *(const bf16x8*)(vr + (csw ^ 4) * 8);
        O[st] = __builtin_amdgcn_mfma_f32_16x16x32_bf16(vf0, pf0, O[st], 0, 0, 0);
        O[st] = __builtin_amdgcn_mfma_f32_16x16x32_bf16(vf1, pf1, O[st], 0, 0, 0);
    }
}

// ---------------------------------------------------------------------------
// Flash attention v5: 64-key trips, TWO q-tiles per block sharing the KV
// stream (balanced pairing tA=j, tB=31-j => every causal block does exactly
// 33 compute-units), single-barrier double-buffered K/V prefetch.
// q,k: [B,H,S,64] bf16; vt: [B,H,64,S] bf16; y: [B,S,H*64] bf16.
// LDS: 2x8K (K) + 2x8K (V) + 9K (P) = 41.2 KB -> 3 blocks/CU; grid needs 2.
// ---------------------------------------------------------------------------
__global__ __launch_bounds__(256) void flash_attn(
    const unsigned short* __restrict__ q,
    const unsigned short* __restrict__ k,
    const unsigned short* __restrict__ vt,
    unsigned short* __restrict__ y,
    const int* __restrict__ is_causal,
    const unsigned char* __restrict__ attn_mask)
{
    __shared__ unsigned short Kl[2][64 * 64];
    __shared__ unsigned short Vl[2][64 * 64];
    __shared__ unsigned short Pq[4][16 * 72];

    const int j   = blockIdx.x;              // 0..15 (pair index)
    const int h   = blockIdx.y;
    const int b   = blockIdx.z;
    const int tid = threadIdx.x;
    const int wave = tid >> 6;
    const int lane = tid & 63;
    const int quad = lane >> 4;
    const int l16  = lane & 15;

    const size_t bh = (size_t)b * HH + h;
    const bool causal = (is_causal[0] != 0);
    const int NT = SS / 64;                  // 32
    const int tA = j, tB = NT - 1 - j;       // balanced pair
    const int ntrips = causal ? (tB + 1) : NT;

    // Q fragments (B-operand) for both subtiles
    const unsigned short* qrowA = q + (bh * SS + tA * 64 + wave * 16 + l16) * 64;
    const unsigned short* qrowB = q + (bh * SS + tB * 64 + wave * 16 + l16) * 64;
    const bf16x8 qfA0 = *(const bf16x8*)(qrowA + quad * 8);
    const bf16x8 qfA1 = *(const bf16x8*)(qrowA + 32 + quad * 8);
    const bf16x8 qfB0 = *(const bf16x8*)(qrowB + quad * 8);
    const bf16x8 qfB1 = *(const bf16x8*)(qrowB + 32 + quad * 8);

    const unsigned short* kbase  = k  + bh * SS * 64;   // [key][d]
    const unsigned short* vtbase = vt + bh * 64 * SS;   // [d][s]

    const int Rl  = lane >> 3;
    const int cph = lane & 7;
    const int csw = quad ^ (l16 & 7);

    f32x4 OA[4], OB[4];
    #pragma unroll
    for (int st = 0; st < 4; ++st) {
        OA[st] = (f32x4){0.f, 0.f, 0.f, 0.f};
        OB[st] = (f32x4){0.f, 0.f, 0.f, 0.f};
    }
    float mA = -1e30f, lA = 0.f, mB = -1e30f, lB = 0.f;

    const int qgA = tA * 64 + wave * 16 + l16;
    const int qgB = tB * 64 + wave * 16 + l16;

    // stage K/V tile kt into buffer kt&1 (4 issues per wave)
    auto stage = [&](int kt) {
        const int buf = kt & 1;
        #pragma unroll
        for (int i = 0; i < 2; ++i) {
            const int jj = wave * 2 + i;
            const int R  = jj * 8 + Rl;
            const int cl = cph ^ (R & 7);
            gload_lds16(kbase + ((size_t)(kt * 64 + R) * 64 + cl * 8),
                        &Kl[buf][jj * 512]);
            gload_lds16(vtbase + ((size_t)R * SS + kt * 64 + cl * 8),
                        &Vl[buf][jj * 512]);
        }
    };

    stage(0);
    for (int kt = 0; kt < ntrips; ++kt) {
        __syncthreads();                     // stage(kt) visible; prev reads done
        if (kt + 1 < ntrips) stage(kt + 1);  // prefetch into other buffer

        const unsigned short* Kb = Kl[kt & 1];
        const unsigned short* Vb = Vl[kt & 1];
        const unsigned char* mrow = causal ? nullptr
                                           : (attn_mask + (size_t)b * SS + kt * 64);

        if (!causal || kt <= tA)
            attn_step(Kb, Vb, Pq[wave], qfA0, qfA1, OA, mA, lA,
                      causal && kt == tA, mrow, kt, quad, l16, csw, qgA);
        attn_step(Kb, Vb, Pq[wave], qfB0, qfB1, OB, mB, lB,
                  causal && kt == tB, mrow, kt, quad, l16, csw, qgB);
    }

    // epilogue: lane owns q=qgA/qgB, d = st*16+quad*4+r
    const float invA = 1.0f / lA;
    unsigned short* yrowA = y + ((size_t)b * SS + qgA) * DD + h * 64;
    #pragma unroll
    for (int st = 0; st < 4; ++st) {
        uint2 o;
        o.x = pack2bf(OA[st][0] * invA, OA[st][1] * invA);
        o.y = pack2bf(OA[st][2] * invA, OA[st][3] * invA);
        *(uint2*)(yrowA + st * 16 + quad * 4) = o;
    }
    const float invB = 1.0f / lB;
    unsigned short* yrowB = y + ((size_t)b * SS + qgB) * DD + h * 64;
    #pragma unroll
    for (int st = 0; st < 4; ++st) {
        uint2 o;
        o.x = pack2bf(OB[st][0] * invB, OB[st][1] * invB);
        o.y = pack2bf(OB[st][2] * invB, OB[st][3] * invB);
        *(uint2*)(yrowB + st * 16 + quad * 4) = o;
    }
}

// ---------------------------------------------------------------------------
// Workspace: xb/yb (aliased) | w1t | w2t | qkv | qb | kb | vt | tab. ~67.6 MB.
// ---------------------------------------------------------------------------
extern "C" void kernel_launch(void* const* d_in, const int* in_sizes, int n_in,
                              void* d_out, int out_size, void* d_ws, size_t ws_size,
                              hipStream_t stream) {
    const float* x      = (const float*)d_in[0];
    const float* qkv_w  = (const float*)d_in[1];
    const float* out_w  = (const float*)d_in[2];
    const unsigned char* mask = (const unsigned char*)d_in[3];
    const int*   is_c   = (const int*)d_in[4];
    float* out = (float*)d_out;

    unsigned short* xb  = (unsigned short*)d_ws;             // aliased with yb
    unsigned short* w1t = xb  + (size_t)4096 * 1024;
    unsigned short* w2t = w1t + (size_t)3072 * 1024;
    unsigned short* qkv = w2t + (size_t)1024 * 1024;
    unsigned short* qb  = qkv + (size_t)4096 * 3072;
    unsigned short* kb  = qb  + (size_t)BB * HH * SS * 64;
    unsigned short* vt  = kb  + (size_t)BB * HH * SS * 64;
    float2* tab = (float2*)(vt + (size_t)BB * HH * SS * 64);
    unsigned short* yb = xb;   // x dead after GEMM1

    sincos_tab<<<(SS * 32) / 256, 256, 0, stream>>>(tab);
    cast_f32_bf16<<<(4096 * 1024) / 1024, 256, 0, stream>>>(x, xb);
    cast_transpose<<<dim3(N3 / 64, DD / 64), 256, 0, stream>>>(qkv_w, w1t, DD, N3);
    cast_transpose<<<dim3(DD / 64, DD / 64), 256, 0, stream>>>(out_w, w2t, DD, DD);

    // GEMM1: qkv = x @ qkv_w  (M=4096, N=3072, K=1024), tile 128x128
    gemm_mfma<unsigned short, 128><<<dim3(N3 / 128, 4096 / 128), 256, 0, stream>>>(
        xb, w1t, qkv, 4096, N3, DD);

    // RoPE + split: q,k [B,H,S,64]; v^T [B,H,64,S]
    rope_split<<<dim3(SS / 64, HH, BB), 256, 0, stream>>>(qkv, tab, qb, kb, vt);

    // Flash attention v5 (paired q-tiles, dbuf prefetch) -> y [B,S,D] bf16
    flash_attn<<<dim3(SS / 128, HH, BB), 256, 0, stream>>>(qb, kb, vt, yb, is_c, mask);

    // GEMM2: out = y @ out_w  (M=4096, N=1024, K=1024), tile 128x64 -> 512 blocks
    gemm_mfma<float, 64><<<dim3(DD / 64, 4096 / 128), 256, 0, stream>>>(
        yb, w2t, out, 4096, DD, DD);
}